// Round 4
// baseline (1164.128 us; speedup 1.0000x reference)
//
#include <hip/hip_runtime.h>
#include <hip/hip_bf16.h>
#include <math.h>

// Problem constants (fixed by the reference)
constexpr int BSZ       = 64;
constexpr int SEQL      = 576;
constexpr int FTIN      = 768;
constexpr int HID       = 512;
constexpr int NNODE     = SEQL + 1;          // 577
constexpr int NUM_NODES = BSZ * NNODE;       // 36928
constexpr int MROWS     = BSZ * SEQL;        // 36864

using b8 = __attribute__((ext_vector_type(8))) __bf16;
using f4 = __attribute__((ext_vector_type(4))) float;
typedef unsigned short u16;

__device__ __forceinline__ float gelu_f(float x) {
    float x3 = x * x * x;
    return 0.5f * x * (1.0f + tanhf(0.7978845608028654f * (x + 0.044715f * x3)));
}
__device__ __forceinline__ float lrelu(float x) {
    return x > 0.0f ? x : 0.2f * x;
}
__device__ __forceinline__ u16 f2bf(float v) {
    __hip_bfloat16 b = __float2bfloat16(v);   // RNE
    return __builtin_bit_cast(u16, b);
}
__device__ __forceinline__ float bf2f(u16 u) {
    return __bfloat162float(__builtin_bit_cast(__hip_bfloat16, u));
}
__device__ __forceinline__ void split_bf(float v, u16& h, u16& l) {
    h = f2bf(v);
    l = f2bf(v - bf2f(h));
}
__device__ __forceinline__ void gl16(const void* g, void* l) {
    __builtin_amdgcn_global_load_lds(
        (const __attribute__((address_space(1))) unsigned int*)g,
        (__attribute__((address_space(3))) unsigned int*)l, 16, 0, 0);
}
__device__ __forceinline__ f4 mfma16(b8 a, b8 b, f4 c) {
    return __builtin_amdgcn_mfma_f32_16x16x32_bf16(a, b, c, 0, 0, 0);
}

// ---------------------------------------------------------------------------
// Weight prep: W fp32 [K x N] -> W^T hi/lo bf16 [N x K]
// ---------------------------------------------------------------------------
__global__ __launch_bounds__(256) void transpose_split_k(
    const float* __restrict__ W, u16* __restrict__ Th,
    u16* __restrict__ Tl, int K, int N)
{
    __shared__ float t[64][65];
    const int kb = blockIdx.x * 64, nb = blockIdx.y * 64;
    for (int i = threadIdx.x; i < 64 * 64; i += 256) {
        int r = i >> 6, c = i & 63;
        t[r][c] = W[(size_t)(kb + r) * N + nb + c];
    }
    __syncthreads();
    for (int i = threadIdx.x; i < 64 * 64; i += 256) {
        int r = i >> 6, c = i & 63;          // r: n index, c: k index
        float v = t[c][r];
        u16 h, l; split_bf(v, h, l);
        Th[(size_t)(nb + r) * K + kb + c] = h;
        Tl[(size_t)(nb + r) * K + kb + c] = l;
    }
}

// ---------------------------------------------------------------------------
// Fused bias: out[n] = (pb ? pb @ W_n : 0) + bias_n, n in [0,1024)
// W_n / bias_n choose A-half (n<512) or B-half.
// ---------------------------------------------------------------------------
__global__ __launch_bounds__(256) void fuse_bias_k(
    const float* __restrict__ pb,
    const float* __restrict__ wA, const float* __restrict__ wB,
    const float* __restrict__ bA, const float* __restrict__ bB,
    float* __restrict__ out)
{
    const int n = blockIdx.x * 256 + threadIdx.x;   // grid 4
    const float* W = (n < 512) ? wA : wB;
    const int c = n & 511;
    float acc = 0.0f;
    if (pb) {
        for (int j = 0; j < 512; j++) acc = fmaf(pb[j], W[(size_t)j * 512 + c], acc);
    }
    out[n] = acc + ((n < 512) ? bA[c] : bB[c]);
}

// ---------------------------------------------------------------------------
// node-0 projection rows: XL/XR[b*577] = pooled[b] @ {wl,wr} + {bl,br}
// ---------------------------------------------------------------------------
__global__ __launch_bounds__(256) void node0_proj_k(
    const float* __restrict__ pooled,
    const float* __restrict__ wl, const float* __restrict__ wr,
    const float* __restrict__ bl, const float* __restrict__ br,
    float* __restrict__ XL, float* __restrict__ XR)
{
    const int b = blockIdx.x;                        // 64
    const int n = blockIdx.y * 256 + threadIdx.x;    // grid.y = 4 -> n < 1024
    __shared__ float p[HID];
    for (int k = threadIdx.x; k < HID; k += 256) p[k] = pooled[b * HID + k];
    __syncthreads();
    const float* W = (n < 512) ? wl : wr;
    const int c = n & 511;
    float acc = 0.0f;
    for (int k = 0; k < HID; k++) acc = fmaf(p[k], W[(size_t)k * 512 + c], acc);
    acc += (n < 512) ? bl[c] : br[c];
    const size_t row = (size_t)b * NNODE * HID;
    if (n < 512) XL[row + c] = acc; else XR[row + c] = acc;
}

// ---------------------------------------------------------------------------
// MFMA GEMM, hi/lo bf16 split (3-product), k-major conflict-free LDS regions,
// double-buffered with single-barrier prefetch (T3-minimal).
// LDS region = 16 rows x 32 k-shorts = 64 granules of 16B; granule g holds
// (row g&15, k-chunk g>>4)  =>  MFMA fragment read is base + lane*16 (linear).
// MODE: 1 = gelu -> hi/lo bf16 (G1)
//       3 = transposed hi/lo write [N][K], no bias (weight-fusion prep)
//       4 = fp32 pair (XL cols 0-511 / XR cols 512-1023), row remap seq->node
//       5 = fp32 pair, plain rows with tail guard
// ---------------------------------------------------------------------------
template<int MODE, bool AF32>
__global__ __launch_bounds__(256, 2) void bgemm(
    const u16* __restrict__ Ah, const u16* __restrict__ Al,
    const float* __restrict__ Af,
    const u16* __restrict__ BTh, const u16* __restrict__ BTl,
    const float* __restrict__ bias,
    float* __restrict__ CfL, float* __restrict__ CfR,
    u16* __restrict__ Ch, u16* __restrict__ Cl,
    int M, int K)
{
    __shared__ u16 lds[2][4][4096];   // [dbuf][Ah,Al,Bh,Bl][8 regions x 512]

    const int tid  = threadIdx.x;
    const int wid  = tid >> 6, lane = tid & 63;
    const int wr   = wid >> 1, wc = wid & 1;
    const int lrow = lane & 15, lk = lane >> 4;
    const int row0 = blockIdx.x * 128, col0 = blockIdx.y * 128;
    const int nt   = K >> 5;

    f4 acc[4][4] = {};
    float4 areg[4];

    // stage one K-step tile into buffer `buf` (B always; A if !AF32)
    auto STAGE = [&](int buf, int k0) {
#pragma unroll
        for (int i = 0; i < 2; i++) {
            const int r = wid * 2 + i;                       // region 0..7
            const int bcol = col0 + r * 16 + lrow;
            const size_t bgo = (size_t)bcol * K + k0 + lk * 8;
            gl16(BTh + bgo, &lds[buf][2][r * 512]);
            gl16(BTl + bgo, &lds[buf][3][r * 512]);
            if constexpr (!AF32) {
                int grow = row0 + r * 16 + lrow;
                if (grow >= M) grow = M - 1;                 // tail clamp
                const size_t ago = (size_t)grow * K + k0 + lk * 8;
                gl16(Ah + ago, &lds[buf][0][r * 512]);
                gl16(Al + ago, &lds[buf][1][r * 512]);
            }
        }
    };
    auto ALOAD = [&](int k0) {
#pragma unroll
        for (int q = 0; q < 4; q++) {
            const int ch = tid * 4 + q;                      // 0..1023
            const int r = ch >> 3, c4 = ch & 7;
            areg[q] = *(const float4*)(Af + (size_t)(row0 + r) * K + k0 + c4 * 4);
        }
    };
    auto AWRITE = [&](int buf) {
#pragma unroll
        for (int q = 0; q < 4; q++) {
            const int ch = tid * 4 + q;
            const int r = ch >> 3, c4 = ch & 7;
            u16 h0, l0, h1, l1, h2, l2, h3, l3;
            split_bf(areg[q].x, h0, l0); split_bf(areg[q].y, h1, l1);
            split_bf(areg[q].z, h2, l2); split_bf(areg[q].w, h3, l3);
            const int off = (r >> 4) * 512 + ((c4 >> 1) * 16 + (r & 15)) * 8 + (c4 & 1) * 4;
            *(ushort4*)&lds[buf][0][off] = make_ushort4(h0, h1, h2, h3);
            *(ushort4*)&lds[buf][1][off] = make_ushort4(l0, l1, l2, l3);
        }
    };

    // prologue
    if constexpr (AF32) { ALOAD(0); AWRITE(0); }
    STAGE(0, 0);
    __syncthreads();

    for (int t = 0; t < nt; t++) {
        const int cur = t & 1;
        const bool more = (t + 1 < nt);
        if (more) {
            if constexpr (AF32) ALOAD((t + 1) << 5);
            STAGE(cur ^ 1, (t + 1) << 5);          // prefetch next tile
        }
        // compute on lds[cur]: fragment read = base + lane*16B (conflict-free)
        b8 a_h[4], b_h[4], tmp[4];
#pragma unroll
        for (int m = 0; m < 4; m++) a_h[m] = *(const b8*)&lds[cur][0][(wr * 4 + m) * 512 + lane * 8];
#pragma unroll
        for (int n = 0; n < 4; n++) b_h[n] = *(const b8*)&lds[cur][2][(wc * 4 + n) * 512 + lane * 8];
#pragma unroll
        for (int m = 0; m < 4; m++)
#pragma unroll
            for (int n = 0; n < 4; n++)
                acc[m][n] = mfma16(a_h[m], b_h[n], acc[m][n]);
        // A_lo x B_hi
#pragma unroll
        for (int m = 0; m < 4; m++) tmp[m] = *(const b8*)&lds[cur][1][(wr * 4 + m) * 512 + lane * 8];
#pragma unroll
        for (int m = 0; m < 4; m++)
#pragma unroll
            for (int n = 0; n < 4; n++)
                acc[m][n] = mfma16(tmp[m], b_h[n], acc[m][n]);
        // A_hi x B_lo
#pragma unroll
        for (int n = 0; n < 4; n++) tmp[n] = *(const b8*)&lds[cur][3][(wc * 4 + n) * 512 + lane * 8];
#pragma unroll
        for (int m = 0; m < 4; m++)
#pragma unroll
            for (int n = 0; n < 4; n++)
                acc[m][n] = mfma16(a_h[m], tmp[n], acc[m][n]);

        if constexpr (AF32) { if (more) AWRITE(cur ^ 1); }
        __syncthreads();   // drains vmcnt (prefetch) + lgkm; one barrier/K-step
    }

    // ---- epilogue. D frag: row = 4*lk + reg, col = lrow (m89 layout)
    const int gcolbase = col0 + wc * 64;
    float biasn[4];
    if constexpr (MODE != 3) {
#pragma unroll
        for (int n = 0; n < 4; n++) biasn[n] = bias[gcolbase + n * 16 + lrow];
    }

#pragma unroll
    for (int m = 0; m < 4; m++) {
#pragma unroll
        for (int r = 0; r < 4; r++) {
            const int grow = row0 + wr * 64 + m * 16 + lk * 4 + r;
            if (MODE != 5 || grow < M) {
#pragma unroll
                for (int n = 0; n < 4; n++) {
                    const int gcol = gcolbase + n * 16 + lrow;
                    float v = acc[m][n][r];
                    if constexpr (MODE == 1) {
                        v = gelu_f(v + biasn[n]);
                        u16 h, l; split_bf(v, h, l);
                        Ch[(size_t)grow * HID + gcol] = h;
                        Cl[(size_t)grow * HID + gcol] = l;
                    } else if constexpr (MODE == 3) {
                        u16 h, l; split_bf(v, h, l);
                        Ch[(size_t)gcol * 512 + grow] = h;
                        Cl[(size_t)gcol * 512 + grow] = l;
                    } else {
                        v += biasn[n];
                        const int orow = (MODE == 4) ? (grow + grow / SEQL + 1) : grow;
                        if (gcol < 512) CfL[(size_t)orow * HID + gcol] = v;
                        else            CfR[(size_t)orow * HID + gcol - 512] = v;
                    }
                }
            }
        }
    }
}

// ---------------------------------------------------------------------------
// GAT combine, dst j >= 1: softmax over {src=0, src=j}. One block per node.
// ---------------------------------------------------------------------------
template<int HEADS, bool GELU, bool OSPLIT>
__global__ __launch_bounds__(256) void gat_edge_k(
    const float* __restrict__ xl, const float* __restrict__ xr,
    const float* __restrict__ att, const float* __restrict__ bias,
    float* __restrict__ outF, u16* __restrict__ outH, u16* __restrict__ outL)
{
    const int b = blockIdx.x / SEQL;
    const int j = blockIdx.x % SEQL;
    const size_t row0 = (size_t)(b * NNODE) * HID;
    const size_t rowj = (size_t)(b * NNODE + 1 + j) * HID;
    const int t = threadIdx.x;
    const int c = 2 * t;

    const float2 xl0  = *(const float2*)(xl + row0 + c);
    const float2 xljv = *(const float2*)(xl + rowj + c);
    const float2 xrjv = *(const float2*)(xr + rowj + c);
    const float2 attc = *(const float2*)(att + c);

    float e0 = attc.x * lrelu(xl0.x + xrjv.x) + attc.y * lrelu(xl0.y + xrjv.y);
    float e1 = attc.x * lrelu(xljv.x + xrjv.x) + attc.y * lrelu(xljv.y + xrjv.y);

#pragma unroll
    for (int off = 32; off; off >>= 1) {
        e0 += __shfl_down(e0, off, 64);
        e1 += __shfl_down(e1, off, 64);
    }
    __shared__ float s0[4], s1[4];
    const int w = t >> 6, lane = t & 63;
    if (lane == 0) { s0[w] = e0; s1[w] = e1; }
    __syncthreads();

    float E0, E1;
    if (HEADS == 4) { E0 = s0[w]; E1 = s1[w]; }
    else            { E0 = s0[0] + s0[1] + s0[2] + s0[3];
                      E1 = s1[0] + s1[1] + s1[2] + s1[3]; }

    const float m  = fmaxf(E0, E1);
    const float p0 = expf(E0 - m);
    const float p1 = expf(E1 - m);
    const float inv = 1.0f / (p0 + p1 + 1e-16f);
    const float a0 = p0 * inv, a1 = p1 * inv;

    float ox = a0 * xl0.x + a1 * xljv.x + bias[c + 0];
    float oy = a0 * xl0.y + a1 * xljv.y + bias[c + 1];
    if (GELU) { ox = gelu_f(ox); oy = gelu_f(oy); }
    if constexpr (OSPLIT) {
        u16 h0, l0, h1, l1;
        split_bf(ox, h0, l0); split_bf(oy, h1, l1);
        *(ushort2*)&outH[rowj + c] = make_ushort2(h0, h1);
        *(ushort2*)&outL[rowj + c] = make_ushort2(l0, l1);
    } else {
        *(float2*)(outF + rowj + c) = make_float2(ox, oy);
    }
}

// ---------------------------------------------------------------------------
// GAT combine, dst node 0: softmax over all 577 sources. Block per (b, head).
// ---------------------------------------------------------------------------
template<int HEADS, bool GELU, bool OSPLIT>
__global__ __launch_bounds__(256) void gat_node0_k(
    const float* __restrict__ xl, const float* __restrict__ xr,
    const float* __restrict__ att, const float* __restrict__ bias,
    float* __restrict__ outF, u16* __restrict__ outH, u16* __restrict__ outL)
{
    constexpr int CH = HID / HEADS;
    const int b = blockIdx.x;
    const int h = blockIdx.y;
    const int t = threadIdx.x;
    const size_t base = (size_t)(b * NNODE) * HID;

    __shared__ float xr0s[CH];
    __shared__ float es[NNODE];
    __shared__ float red[256];

    const float* atth = att + h * CH;
    for (int c = t; c < CH; c += 256) xr0s[c] = xr[base + h * CH + c];
    __syncthreads();

    for (int s = t; s < NNODE; s += 256) {
        const float* xls = xl + base + (size_t)s * HID + h * CH;
        float e = 0.0f;
        for (int c = 0; c < CH; c += 4) {
            float4 v = *(const float4*)(xls + c);
            float4 a = *(const float4*)(atth + c);
            e = fmaf(a.x, lrelu(v.x + xr0s[c + 0]), e);
            e = fmaf(a.y, lrelu(v.y + xr0s[c + 1]), e);
            e = fmaf(a.z, lrelu(v.z + xr0s[c + 2]), e);
            e = fmaf(a.w, lrelu(v.w + xr0s[c + 3]), e);
        }
        es[s] = e;
    }
    __syncthreads();

    float m = -INFINITY;
    for (int s = t; s < NNODE; s += 256) m = fmaxf(m, es[s]);
    red[t] = m; __syncthreads();
    for (int off = 128; off; off >>= 1) {
        if (t < off) red[t] = fmaxf(red[t], red[t + off]);
        __syncthreads();
    }
    m = red[0];
    __syncthreads();

    float sum = 0.0f;
    for (int s = t; s < NNODE; s += 256) {
        float p = expf(es[s] - m);
        es[s] = p;
        sum += p;
    }
    red[t] = sum; __syncthreads();
    for (int off = 128; off; off >>= 1) {
        if (t < off) red[t] += red[t + off];
        __syncthreads();
    }
    const float invS = 1.0f / (red[0] + 1e-16f);

    for (int c = t; c < CH; c += 256) {
        float acc = 0.0f;
        for (int s = 0; s < NNODE; s++)
            acc = fmaf(es[s], xl[base + (size_t)s * HID + h * CH + c], acc);
        float o = acc * invS + bias[h * CH + c];
        if (GELU) o = gelu_f(o);
        if constexpr (OSPLIT) {
            u16 hh, ll; split_bf(o, hh, ll);
            outH[base + h * CH + c] = hh;
            outL[base + h * CH + c] = ll;
        } else {
            outF[base + h * CH + c] = o;
        }
    }
}

// ---------------------------------------------------------------------------
__global__ __launch_bounds__(256) void mean_k(const float* __restrict__ h2,
                                              float* __restrict__ out)
{
    const int b = blockIdx.x;
    const int c = blockIdx.y * 256 + threadIdx.x;
    const float* p = h2 + (size_t)(b * NNODE) * HID + c;
    float s = 0.0f;
    for (int i = 0; i < NNODE; i++) s += p[(size_t)i * HID];
    out[(size_t)BSZ * HID + b * HID + c] = s * (1.0f / NNODE);
}

__global__ __launch_bounds__(256) void head_k(
    const float* __restrict__ h2, const float* __restrict__ linw,
    const float* __restrict__ linb, const float* __restrict__ pooled,
    float* __restrict__ out)
{
    const int b = blockIdx.x;
    const int col = blockIdx.y * 256 + threadIdx.x;
    __shared__ float cls[HID];
    for (int k = threadIdx.x; k < HID; k += 256)
        cls[k] = h2[(size_t)(b * NNODE) * HID + k];
    __syncthreads();
    float acc = 0.0f;
    for (int k = 0; k < HID; k++)
        acc = fmaf(cls[k], linw[(size_t)k * HID + col], acc);
    out[b * HID + col] = acc + linb[col] + pooled[b * HID + col];
}

// ---------------------------------------------------------------------------
extern "C" void kernel_launch(void* const* d_in, const int* in_sizes, int n_in,
                              void* d_out, int out_size, void* d_ws, size_t ws_size,
                              hipStream_t stream)
{
    const float* hs     = (const float*)d_in[0];
    const float* pooled = (const float*)d_in[1];
    const float* pw1  = (const float*)d_in[2];  const float* pb1   = (const float*)d_in[3];
    const float* pw2  = (const float*)d_in[4];  const float* pb2   = (const float*)d_in[5];
    const float* wl1  = (const float*)d_in[6];  const float* bl1   = (const float*)d_in[7];
    const float* wr1  = (const float*)d_in[8];  const float* br1   = (const float*)d_in[9];
    const float* att1 = (const float*)d_in[10]; const float* bias1 = (const float*)d_in[11];
    const float* wl2  = (const float*)d_in[12]; const float* bl2   = (const float*)d_in[13];
    const float* wr2  = (const float*)d_in[14]; const float* br2   = (const float*)d_in[15];
    const float* att2 = (const float*)d_in[16]; const float* bias2 = (const float*)d_in[17];
    const float* linw = (const float*)d_in[18]; const float* linb  = (const float*)d_in[19];
    float* out = (float*)d_out;

    // ---- workspace arena: 3 rotating 72 MiB regions + 4 MB weight region
    char* ws = (char*)d_ws;
    const size_t RSZ = 75637760;
    char* R0 = ws;                 // hH/hL -> h1H/h1L -> h2(f32)
    char* R1 = ws + RSZ;           // [prep scratch] -> xl1_f -> xl2_f
    char* R2 = ws + 2 * RSZ;       // xr1_f -> xr2_f
    u16*  Wr = (u16*)(ws + 3 * RSZ);

    // R0 tenants
    u16* hH  = (u16*)R0;
    u16* hL  = hH + (size_t)MROWS * HID;
    u16* h1H = (u16*)R0;
    u16* h1L = h1H + (size_t)NUM_NODES * HID;
    float* h2 = (float*)R0;
    // R1/R2 tenants
    float* XL = (float*)R1;
    float* XR = (float*)R2;
    // prep scratch inside R1 (consumed before XL is written)
    u16* prepBT_h = (u16*)R1;                       // [1024][512]
    u16* prepBT_l = prepBT_h + 1024 * 512;
    u16* pw1T_h   = prepBT_l + 1024 * 512;          // [512][768]
    u16* pw1T_l   = pw1T_h + 512 * FTIN;
    // persistent weight region (~4 MB + 8 KB)
    u16* W1Th = Wr;                                 // fused pw2@[wl1|wr1], [1024][512]
    u16* W1Tl = W1Th + 1024 * 512;
    u16* BT2h = W1Tl + 1024 * 512;                  // [wl2|wr2]^T, [1024][512]
    u16* BT2l = BT2h + 1024 * 512;
    float* fb1 = (float*)(BT2l + 1024 * 512);       // fused bias layer1 [1024]
    float* fb2 = fb1 + 1024;                        // concat bias layer2 [1024]

    const dim3 blk(256);

    // 0) weight prep
    transpose_split_k<<<dim3(8, 8), blk, 0, stream>>>(wl1, prepBT_h, prepBT_l, HID, HID);
    transpose_split_k<<<dim3(8, 8), blk, 0, stream>>>(wr1, prepBT_h + 512 * 512, prepBT_l + 512 * 512, HID, HID);
    transpose_split_k<<<dim3(12, 8), blk, 0, stream>>>(pw1, pw1T_h, pw1T_l, FTIN, HID);
    transpose_split_k<<<dim3(8, 8), blk, 0, stream>>>(wl2, BT2h, BT2l, HID, HID);
    transpose_split_k<<<dim3(8, 8), blk, 0, stream>>>(wr2, BT2h + 512 * 512, BT2l + 512 * 512, HID, HID);
    // W1' = pw2 @ [wl1|wr1], written transposed hi/lo (MODE 3)
    bgemm<3, true><<<dim3(4, 8), blk, 0, stream>>>(nullptr, nullptr, pw2, prepBT_h, prepBT_l,
                                                   nullptr, nullptr, nullptr, W1Th, W1Tl, 512, HID);
    fuse_bias_k<<<dim3(4), blk, 0, stream>>>(pb2, wl1, wr1, bl1, br1, fb1);
    fuse_bias_k<<<dim3(4), blk, 0, stream>>>(nullptr, wl2, wr2, bl2, br2, fb2);

    // 1) h = gelu(hs @ pw1 + pb1) -> hH/hL (R0)
    bgemm<1, true><<<dim3(288, 4), blk, 0, stream>>>(nullptr, nullptr, hs, pw1T_h, pw1T_l,
                                                     pb1, nullptr, nullptr, hH, hL, MROWS, FTIN);
    // 2) fused GAT1 projections: xl1|xr1 = h @ W1' + fb1 (row remap seq->node)
    bgemm<4, false><<<dim3(288, 8), blk, 0, stream>>>(hH, hL, nullptr, W1Th, W1Tl,
                                                      fb1, XL, XR, nullptr, nullptr, MROWS, HID);
    node0_proj_k<<<dim3(BSZ, 4), blk, 0, stream>>>(pooled, wl1, wr1, bl1, br1, XL, XR);
    // 3) GAT1 combine (+bias, gelu) -> h1H/h1L (R0)
    gat_edge_k<4, true, true><<<dim3(MROWS), blk, 0, stream>>>(XL, XR, att1, bias1,
                                                               nullptr, h1H, h1L);
    gat_node0_k<4, true, true><<<dim3(BSZ, 4), blk, 0, stream>>>(XL, XR, att1, bias1,
                                                                 nullptr, h1H, h1L);
    // 4) fused GAT2 projections: xl2|xr2 = h1 @ [wl2|wr2] + [bl2|br2]
    bgemm<5, false><<<dim3(289, 8), blk, 0, stream>>>(h1H, h1L, nullptr, BT2h, BT2l,
                                                      fb2, XL, XR, nullptr, nullptr, NUM_NODES, HID);
    // 5) GAT2 combine (+bias) -> h2 f32 (R0)
    gat_edge_k<1, false, false><<<dim3(MROWS), blk, 0, stream>>>(XL, XR, att2, bias2,
                                                                 h2, nullptr, nullptr);
    gat_node0_k<1, false, false><<<dim3(BSZ, 1), blk, 0, stream>>>(XL, XR, att2, bias2,
                                                                   h2, nullptr, nullptr);
    // 6) outputs
    head_k<<<dim3(BSZ, 2), blk, 0, stream>>>(h2, linw, linb, pooled, out);
    mean_k<<<dim3(BSZ, 2), blk, 0, stream>>>(h2, out);
}

// Round 5
// 1077.839 us; speedup vs baseline: 1.0801x; 1.0801x over previous
//
#include <hip/hip_runtime.h>
#include <hip/hip_bf16.h>
#include <math.h>

// Problem constants (fixed by the reference)
constexpr int BSZ       = 64;
constexpr int SEQL      = 576;
constexpr int FTIN      = 768;
constexpr int HID       = 512;
constexpr int NNODE     = SEQL + 1;          // 577
constexpr int NUM_NODES = BSZ * NNODE;       // 36928
constexpr int MROWS     = BSZ * SEQL;        // 36864

using b8 = __attribute__((ext_vector_type(8))) __bf16;
using f4 = __attribute__((ext_vector_type(4))) float;
typedef unsigned short u16;

__device__ __forceinline__ float gelu_f(float x) {
    float x3 = x * x * x;
    return 0.5f * x * (1.0f + tanhf(0.7978845608028654f * (x + 0.044715f * x3)));
}
__device__ __forceinline__ float lrelu(float x) {
    return x > 0.0f ? x : 0.2f * x;
}
__device__ __forceinline__ u16 f2bf(float v) {
    __hip_bfloat16 b = __float2bfloat16(v);   // RNE
    return __builtin_bit_cast(u16, b);
}
__device__ __forceinline__ float bf2f(u16 u) {
    return __bfloat162float(__builtin_bit_cast(__hip_bfloat16, u));
}
__device__ __forceinline__ void split_bf(float v, u16& h, u16& l) {
    h = f2bf(v);
    l = f2bf(v - bf2f(h));
}
__device__ __forceinline__ void gl16(const void* g, void* l) {
    __builtin_amdgcn_global_load_lds(
        (const __attribute__((address_space(1))) unsigned int*)g,
        (__attribute__((address_space(3))) unsigned int*)l, 16, 0, 0);
}
__device__ __forceinline__ f4 mfma16(b8 a, b8 b, f4 c) {
    return __builtin_amdgcn_mfma_f32_16x16x32_bf16(a, b, c, 0, 0, 0);
}

// ---------------------------------------------------------------------------
// Weight prep: W fp32 [K x N] -> W^T hi/lo bf16 [N x K]
// ---------------------------------------------------------------------------
__global__ __launch_bounds__(256) void transpose_split_k(
    const float* __restrict__ W, u16* __restrict__ Th,
    u16* __restrict__ Tl, int K, int N)
{
    __shared__ float t[64][65];
    const int kb = blockIdx.x * 64, nb = blockIdx.y * 64;
    for (int i = threadIdx.x; i < 64 * 64; i += 256) {
        int r = i >> 6, c = i & 63;
        t[r][c] = W[(size_t)(kb + r) * N + nb + c];
    }
    __syncthreads();
    for (int i = threadIdx.x; i < 64 * 64; i += 256) {
        int r = i >> 6, c = i & 63;          // r: n index, c: k index
        float v = t[c][r];
        u16 h, l; split_bf(v, h, l);
        Th[(size_t)(nb + r) * K + kb + c] = h;
        Tl[(size_t)(nb + r) * K + kb + c] = l;
    }
}

// ---------------------------------------------------------------------------
// Fused bias: out[n] = (pb ? pb @ W_n : 0) + bias_n, n in [0,1024)
// ---------------------------------------------------------------------------
__global__ __launch_bounds__(256) void fuse_bias_k(
    const float* __restrict__ pb,
    const float* __restrict__ wA, const float* __restrict__ wB,
    const float* __restrict__ bA, const float* __restrict__ bB,
    float* __restrict__ out)
{
    const int n = blockIdx.x * 256 + threadIdx.x;   // grid 4
    const float* W = (n < 512) ? wA : wB;
    const int c = n & 511;
    float acc = 0.0f;
    if (pb) {
        for (int j = 0; j < 512; j++) acc = fmaf(pb[j], W[(size_t)j * 512 + c], acc);
    }
    out[n] = acc + ((n < 512) ? bA[c] : bB[c]);
}

// ---------------------------------------------------------------------------
// node-0 projection rows: XL/XR[b*577] = pooled[b] @ {wl,wr} + {bl,br}
// ---------------------------------------------------------------------------
__global__ __launch_bounds__(256) void node0_proj_k(
    const float* __restrict__ pooled,
    const float* __restrict__ wl, const float* __restrict__ wr,
    const float* __restrict__ bl, const float* __restrict__ br,
    float* __restrict__ XL, float* __restrict__ XR)
{
    const int b = blockIdx.x;                        // 64
    const int n = blockIdx.y * 256 + threadIdx.x;    // grid.y = 4 -> n < 1024
    __shared__ float p[HID];
    for (int k = threadIdx.x; k < HID; k += 256) p[k] = pooled[b * HID + k];
    __syncthreads();
    const float* W = (n < 512) ? wl : wr;
    const int c = n & 511;
    float acc = 0.0f;
    for (int k = 0; k < HID; k++) acc = fmaf(p[k], W[(size_t)k * 512 + c], acc);
    acc += (n < 512) ? bl[c] : br[c];
    const size_t row = (size_t)b * NNODE * HID;
    if (n < 512) XL[row + c] = acc; else XR[row + c] = acc;
}

// ---------------------------------------------------------------------------
// MFMA GEMM, hi/lo bf16 split (3-product), k-major conflict-free LDS regions.
// m97 structure: SINGLE 32 KB buffer, 2 barriers/K-step, occupancy does the
// overlap (5 blocks/CU by LDS). 1D grid, bijective XCD swizzle, col-fastest
// decode so all col-blocks of one A row-panel run on the same XCD (L2 reuse).
// LDS region = 16 rows x 32 k-shorts as 64 granules of 16B; granule g holds
// (row g&15, k-chunk g>>4)  =>  fragment read = base + lane*16B (linear).
// MODE: 1 = gelu -> hi/lo bf16 (G1)
//       3 = transposed hi/lo write [N][K], no bias (weight-fusion prep)
//       4 = fp32 pair (XL cols 0-511 / XR 512-1023), row remap seq->node
//       5 = fp32 pair, plain rows with tail guard
// ---------------------------------------------------------------------------
template<int MODE, bool AF32>
__global__ __launch_bounds__(256, 4) void bgemm(
    const u16* __restrict__ Ah, const u16* __restrict__ Al,
    const float* __restrict__ Af,
    const u16* __restrict__ BTh, const u16* __restrict__ BTl,
    const float* __restrict__ bias,
    float* __restrict__ CfL, float* __restrict__ CfR,
    u16* __restrict__ Ch, u16* __restrict__ Cl,
    int M, int K, int nblk)
{
    __shared__ u16 lds[4][4096];   // [Ah,Al,Bh,Bl][8 regions x 512]

    // 1D grid, bijective XCD swizzle (gridDim.x % 8 == 0 for all call sites)
    const int nwg = gridDim.x;
    const int p = blockIdx.x;
    const int lb = (nwg % 8 == 0) ? (p % 8) * (nwg / 8) + p / 8 : p;
    const int row0 = (lb / nblk) * 128, col0 = (lb % nblk) * 128;

    const int tid  = threadIdx.x;
    const int wid  = tid >> 6, lane = tid & 63;
    const int wr   = wid >> 1, wc = wid & 1;
    const int lrow = lane & 15, lk = lane >> 4;
    const int nt   = K >> 5;

    f4 acc[4][4] = {};
    float4 areg[4];

    for (int t = 0; t < nt; t++) {
        const int k0 = t << 5;

        // ---- stage (async gl16 issues first; reg-loads/ds_writes overlap)
#pragma unroll
        for (int i = 0; i < 2; i++) {
            const int r = wid * 2 + i;                       // region 0..7
            const int bcol = col0 + r * 16 + lrow;
            const size_t bgo = (size_t)bcol * K + k0 + lk * 8;
            gl16(BTh + bgo, &lds[2][r * 512]);
            gl16(BTl + bgo, &lds[3][r * 512]);
            if constexpr (!AF32) {
                int grow = row0 + r * 16 + lrow;
                if (grow >= M) grow = M - 1;                 // tail clamp
                const size_t ago = (size_t)grow * K + k0 + lk * 8;
                gl16(Ah + ago, &lds[0][r * 512]);
                gl16(Al + ago, &lds[1][r * 512]);
            }
        }
        if constexpr (AF32) {
#pragma unroll
            for (int q = 0; q < 4; q++) {
                const int ch = tid * 4 + q;                  // 0..1023
                const int r = ch >> 3, c4 = ch & 7;
                areg[q] = *(const float4*)(Af + (size_t)(row0 + r) * K + k0 + c4 * 4);
            }
#pragma unroll
            for (int q = 0; q < 4; q++) {
                const int ch = tid * 4 + q;
                const int r = ch >> 3, c4 = ch & 7;
                u16 h0, l0, h1, l1, h2, l2, h3, l3;
                split_bf(areg[q].x, h0, l0); split_bf(areg[q].y, h1, l1);
                split_bf(areg[q].z, h2, l2); split_bf(areg[q].w, h3, l3);
                const int off = (r >> 4) * 512 + ((c4 >> 1) * 16 + (r & 15)) * 8 + (c4 & 1) * 4;
                *(ushort4*)&lds[0][off] = make_ushort4(h0, h1, h2, h3);
                *(ushort4*)&lds[1][off] = make_ushort4(l0, l1, l2, l3);
            }
        }
        __syncthreads();   // drains vmcnt (gl16) + lgkm (ds_write)

        // ---- compute: fragment read = base + lane*16B (conflict-free) + 48 MFMA
        b8 a_h[4], b_h[4], tmp[4];
#pragma unroll
        for (int m = 0; m < 4; m++) a_h[m] = *(const b8*)&lds[0][(wr * 4 + m) * 512 + lane * 8];
#pragma unroll
        for (int n = 0; n < 4; n++) b_h[n] = *(const b8*)&lds[2][(wc * 4 + n) * 512 + lane * 8];
#pragma unroll
        for (int m = 0; m < 4; m++)
#pragma unroll
            for (int n = 0; n < 4; n++)
                acc[m][n] = mfma16(a_h[m], b_h[n], acc[m][n]);
        // A_lo x B_hi
#pragma unroll
        for (int m = 0; m < 4; m++) tmp[m] = *(const b8*)&lds[1][(wr * 4 + m) * 512 + lane * 8];
#pragma unroll
        for (int m = 0; m < 4; m++)
#pragma unroll
            for (int n = 0; n < 4; n++)
                acc[m][n] = mfma16(tmp[m], b_h[n], acc[m][n]);
        // A_hi x B_lo
#pragma unroll
        for (int n = 0; n < 4; n++) tmp[n] = *(const b8*)&lds[3][(wc * 4 + n) * 512 + lane * 8];
#pragma unroll
        for (int m = 0; m < 4; m++)
#pragma unroll
            for (int n = 0; n < 4; n++)
                acc[m][n] = mfma16(a_h[m], tmp[n], acc[m][n]);

        __syncthreads();   // LDS reads done before next stage overwrites
    }

    // ---- epilogue. D frag: row = 4*lk + reg, col = lrow (m89 layout)
    const int gcolbase = col0 + wc * 64;
    float biasn[4];
    if constexpr (MODE != 3) {
#pragma unroll
        for (int n = 0; n < 4; n++) biasn[n] = bias[gcolbase + n * 16 + lrow];
    }

#pragma unroll
    for (int m = 0; m < 4; m++) {
#pragma unroll
        for (int r = 0; r < 4; r++) {
            const int grow = row0 + wr * 64 + m * 16 + lk * 4 + r;
            if (MODE != 5 || grow < M) {
#pragma unroll
                for (int n = 0; n < 4; n++) {
                    const int gcol = gcolbase + n * 16 + lrow;
                    float v = acc[m][n][r];
                    if constexpr (MODE == 1) {
                        v = gelu_f(v + biasn[n]);
                        u16 h, l; split_bf(v, h, l);
                        Ch[(size_t)grow * HID + gcol] = h;
                        Cl[(size_t)grow * HID + gcol] = l;
                    } else if constexpr (MODE == 3) {
                        u16 h, l; split_bf(v, h, l);
                        Ch[(size_t)gcol * 512 + grow] = h;
                        Cl[(size_t)gcol * 512 + grow] = l;
                    } else {
                        v += biasn[n];
                        const int orow = (MODE == 4) ? (grow + grow / SEQL + 1) : grow;
                        if (gcol < 512) CfL[(size_t)orow * HID + gcol] = v;
                        else            CfR[(size_t)orow * HID + gcol - 512] = v;
                    }
                }
            }
        }
    }
}

// ---------------------------------------------------------------------------
// GAT combine, dst j >= 1: softmax over {src=0, src=j}. One block per node.
// ---------------------------------------------------------------------------
template<int HEADS, bool GELU, bool OSPLIT>
__global__ __launch_bounds__(256) void gat_edge_k(
    const float* __restrict__ xl, const float* __restrict__ xr,
    const float* __restrict__ att, const float* __restrict__ bias,
    float* __restrict__ outF, u16* __restrict__ outH, u16* __restrict__ outL)
{
    const int b = blockIdx.x / SEQL;
    const int j = blockIdx.x % SEQL;
    const size_t row0 = (size_t)(b * NNODE) * HID;
    const size_t rowj = (size_t)(b * NNODE + 1 + j) * HID;
    const int t = threadIdx.x;
    const int c = 2 * t;

    const float2 xl0  = *(const float2*)(xl + row0 + c);
    const float2 xljv = *(const float2*)(xl + rowj + c);
    const float2 xrjv = *(const float2*)(xr + rowj + c);
    const float2 attc = *(const float2*)(att + c);

    float e0 = attc.x * lrelu(xl0.x + xrjv.x) + attc.y * lrelu(xl0.y + xrjv.y);
    float e1 = attc.x * lrelu(xljv.x + xrjv.x) + attc.y * lrelu(xljv.y + xrjv.y);

#pragma unroll
    for (int off = 32; off; off >>= 1) {
        e0 += __shfl_down(e0, off, 64);
        e1 += __shfl_down(e1, off, 64);
    }
    __shared__ float s0[4], s1[4];
    const int w = t >> 6, lane = t & 63;
    if (lane == 0) { s0[w] = e0; s1[w] = e1; }
    __syncthreads();

    float E0, E1;
    if (HEADS == 4) { E0 = s0[w]; E1 = s1[w]; }
    else            { E0 = s0[0] + s0[1] + s0[2] + s0[3];
                      E1 = s1[0] + s1[1] + s1[2] + s1[3]; }

    const float m  = fmaxf(E0, E1);
    const float p0 = expf(E0 - m);
    const float p1 = expf(E1 - m);
    const float inv = 1.0f / (p0 + p1 + 1e-16f);
    const float a0 = p0 * inv, a1 = p1 * inv;

    float ox = a0 * xl0.x + a1 * xljv.x + bias[c + 0];
    float oy = a0 * xl0.y + a1 * xljv.y + bias[c + 1];
    if (GELU) { ox = gelu_f(ox); oy = gelu_f(oy); }
    if constexpr (OSPLIT) {
        u16 h0, l0, h1, l1;
        split_bf(ox, h0, l0); split_bf(oy, h1, l1);
        *(ushort2*)&outH[rowj + c] = make_ushort2(h0, h1);
        *(ushort2*)&outL[rowj + c] = make_ushort2(l0, l1);
    } else {
        *(float2*)(outF + rowj + c) = make_float2(ox, oy);
    }
}

// ---------------------------------------------------------------------------
// GAT combine, dst node 0: softmax over all 577 sources. Block per (b, head).
// ---------------------------------------------------------------------------
template<int HEADS, bool GELU, bool OSPLIT>
__global__ __launch_bounds__(256) void gat_node0_k(
    const float* __restrict__ xl, const float* __restrict__ xr,
    const float* __restrict__ att, const float* __restrict__ bias,
    float* __restrict__ outF, u16* __restrict__ outH, u16* __restrict__ outL)
{
    constexpr int CH = HID / HEADS;
    const int b = blockIdx.x;
    const int h = blockIdx.y;
    const int t = threadIdx.x;
    const size_t base = (size_t)(b * NNODE) * HID;

    __shared__ float xr0s[CH];
    __shared__ float es[NNODE];
    __shared__ float red[256];

    const float* atth = att + h * CH;
    for (int c = t; c < CH; c += 256) xr0s[c] = xr[base + h * CH + c];
    __syncthreads();

    for (int s = t; s < NNODE; s += 256) {
        const float* xls = xl + base + (size_t)s * HID + h * CH;
        float e = 0.0f;
        for (int c = 0; c < CH; c += 4) {
            float4 v = *(const float4*)(xls + c);
            float4 a = *(const float4*)(atth + c);
            e = fmaf(a.x, lrelu(v.x + xr0s[c + 0]), e);
            e = fmaf(a.y, lrelu(v.y + xr0s[c + 1]), e);
            e = fmaf(a.z, lrelu(v.z + xr0s[c + 2]), e);
            e = fmaf(a.w, lrelu(v.w + xr0s[c + 3]), e);
        }
        es[s] = e;
    }
    __syncthreads();

    float m = -INFINITY;
    for (int s = t; s < NNODE; s += 256) m = fmaxf(m, es[s]);
    red[t] = m; __syncthreads();
    for (int off = 128; off; off >>= 1) {
        if (t < off) red[t] = fmaxf(red[t], red[t + off]);
        __syncthreads();
    }
    m = red[0];
    __syncthreads();

    float sum = 0.0f;
    for (int s = t; s < NNODE; s += 256) {
        float p = expf(es[s] - m);
        es[s] = p;
        sum += p;
    }
    red[t] = sum; __syncthreads();
    for (int off = 128; off; off >>= 1) {
        if (t < off) red[t] += red[t + off];
        __syncthreads();
    }
    const float invS = 1.0f / (red[0] + 1e-16f);

    for (int c = t; c < CH; c += 256) {
        float acc = 0.0f;
        for (int s = 0; s < NNODE; s++)
            acc = fmaf(es[s], xl[base + (size_t)s * HID + h * CH + c], acc);
        float o = acc * invS + bias[h * CH + c];
        if (GELU) o = gelu_f(o);
        if constexpr (OSPLIT) {
            u16 hh, ll; split_bf(o, hh, ll);
            outH[base + h * CH + c] = hh;
            outL[base + h * CH + c] = ll;
        } else {
            outF[base + h * CH + c] = o;
        }
    }
}

// ---------------------------------------------------------------------------
__global__ __launch_bounds__(256) void mean_k(const float* __restrict__ h2,
                                              float* __restrict__ out)
{
    const int b = blockIdx.x;
    const int c = blockIdx.y * 256 + threadIdx.x;
    const float* p = h2 + (size_t)(b * NNODE) * HID + c;
    float s = 0.0f;
    for (int i = 0; i < NNODE; i++) s += p[(size_t)i * HID];
    out[(size_t)BSZ * HID + b * HID + c] = s * (1.0f / NNODE);
}

__global__ __launch_bounds__(256) void head_k(
    const float* __restrict__ h2, const float* __restrict__ linw,
    const float* __restrict__ linb, const float* __restrict__ pooled,
    float* __restrict__ out)
{
    const int b = blockIdx.x;
    const int col = blockIdx.y * 256 + threadIdx.x;
    __shared__ float cls[HID];
    for (int k = threadIdx.x; k < HID; k += 256)
        cls[k] = h2[(size_t)(b * NNODE) * HID + k];
    __syncthreads();
    float acc = 0.0f;
    for (int k = 0; k < HID; k++)
        acc = fmaf(cls[k], linw[(size_t)k * HID + col], acc);
    out[b * HID + col] = acc + linb[col] + pooled[b * HID + col];
}

// ---------------------------------------------------------------------------
extern "C" void kernel_launch(void* const* d_in, const int* in_sizes, int n_in,
                              void* d_out, int out_size, void* d_ws, size_t ws_size,
                              hipStream_t stream)
{
    const float* hs     = (const float*)d_in[0];
    const float* pooled = (const float*)d_in[1];
    const float* pw1  = (const float*)d_in[2];  const float* pb1   = (const float*)d_in[3];
    const float* pw2  = (const float*)d_in[4];  const float* pb2   = (const float*)d_in[5];
    const float* wl1  = (const float*)d_in[6];  const float* bl1   = (const float*)d_in[7];
    const float* wr1  = (const float*)d_in[8];  const float* br1   = (const float*)d_in[9];
    const float* att1 = (const float*)d_in[10]; const float* bias1 = (const float*)d_in[11];
    const float* wl2  = (const float*)d_in[12]; const float* bl2   = (const float*)d_in[13];
    const float* wr2  = (const float*)d_in[14]; const float* br2   = (const float*)d_in[15];
    const float* att2 = (const float*)d_in[16]; const float* bias2 = (const float*)d_in[17];
    const float* linw = (const float*)d_in[18]; const float* linb  = (const float*)d_in[19];
    float* out = (float*)d_out;

    // ---- workspace arena: 3 rotating 72 MiB regions + 4 MB weight region
    char* ws = (char*)d_ws;
    const size_t RSZ = 75637760;
    char* R0 = ws;                 // hH/hL -> h1H/h1L -> h2(f32)
    char* R1 = ws + RSZ;           // [prep scratch] -> xl1_f -> xl2_f
    char* R2 = ws + 2 * RSZ;       // xr1_f -> xr2_f
    u16*  Wr = (u16*)(ws + 3 * RSZ);

    // R0 tenants
    u16* hH  = (u16*)R0;
    u16* hL  = hH + (size_t)MROWS * HID;
    u16* h1H = (u16*)R0;
    u16* h1L = h1H + (size_t)NUM_NODES * HID;
    float* h2 = (float*)R0;
    // R1/R2 tenants
    float* XL = (float*)R1;
    float* XR = (float*)R2;
    // prep scratch inside R1 (consumed before XL is written)
    u16* prepBT_h = (u16*)R1;                       // [1024][512]
    u16* prepBT_l = prepBT_h + 1024 * 512;
    u16* pw1T_h   = prepBT_l + 1024 * 512;          // [512][768]
    u16* pw1T_l   = pw1T_h + 512 * FTIN;
    // persistent weight region (~4 MB + 8 KB)
    u16* W1Th = Wr;                                 // fused pw2@[wl1|wr1], [1024][512]
    u16* W1Tl = W1Th + 1024 * 512;
    u16* BT2h = W1Tl + 1024 * 512;                  // [wl2|wr2]^T, [1024][512]
    u16* BT2l = BT2h + 1024 * 512;
    float* fb1 = (float*)(BT2l + 1024 * 512);       // fused bias layer1 [1024]
    float* fb2 = fb1 + 1024;                        // concat bias layer2 [1024]

    const dim3 blk(256);

    // 0) weight prep
    transpose_split_k<<<dim3(8, 8), blk, 0, stream>>>(wl1, prepBT_h, prepBT_l, HID, HID);
    transpose_split_k<<<dim3(8, 8), blk, 0, stream>>>(wr1, prepBT_h + 512 * 512, prepBT_l + 512 * 512, HID, HID);
    transpose_split_k<<<dim3(12, 8), blk, 0, stream>>>(pw1, pw1T_h, pw1T_l, FTIN, HID);
    transpose_split_k<<<dim3(8, 8), blk, 0, stream>>>(wl2, BT2h, BT2l, HID, HID);
    transpose_split_k<<<dim3(8, 8), blk, 0, stream>>>(wr2, BT2h + 512 * 512, BT2l + 512 * 512, HID, HID);
    // W1' = pw2 @ [wl1|wr1], written transposed hi/lo (MODE 3); 4 rows x 8 cols
    bgemm<3, true><<<dim3(32), blk, 0, stream>>>(nullptr, nullptr, pw2, prepBT_h, prepBT_l,
                                                 nullptr, nullptr, nullptr, W1Th, W1Tl, 512, HID, 8);
    fuse_bias_k<<<dim3(4), blk, 0, stream>>>(pb2, wl1, wr1, bl1, br1, fb1);
    fuse_bias_k<<<dim3(4), blk, 0, stream>>>(nullptr, wl2, wr2, bl2, br2, fb2);

    // 1) h = gelu(hs @ pw1 + pb1) -> hH/hL (R0); 288 rows x 4 cols
    bgemm<1, true><<<dim3(1152), blk, 0, stream>>>(nullptr, nullptr, hs, pw1T_h, pw1T_l,
                                                   pb1, nullptr, nullptr, hH, hL, MROWS, FTIN, 4);
    // 2) fused GAT1 projections: xl1|xr1 = h @ W1' + fb1 (remap); 288 x 8
    bgemm<4, false><<<dim3(2304), blk, 0, stream>>>(hH, hL, nullptr, W1Th, W1Tl,
                                                    fb1, XL, XR, nullptr, nullptr, MROWS, HID, 8);
    node0_proj_k<<<dim3(BSZ, 4), blk, 0, stream>>>(pooled, wl1, wr1, bl1, br1, XL, XR);
    // 3) GAT1 combine (+bias, gelu) -> h1H/h1L (R0)
    gat_edge_k<4, true, true><<<dim3(MROWS), blk, 0, stream>>>(XL, XR, att1, bias1,
                                                               nullptr, h1H, h1L);
    gat_node0_k<4, true, true><<<dim3(BSZ, 4), blk, 0, stream>>>(XL, XR, att1, bias1,
                                                                 nullptr, h1H, h1L);
    // 4) fused GAT2 projections: xl2|xr2 = h1 @ [wl2|wr2] + [bl2|br2]; 289 x 8
    bgemm<5, false><<<dim3(2312), blk, 0, stream>>>(h1H, h1L, nullptr, BT2h, BT2l,
                                                    fb2, XL, XR, nullptr, nullptr, NUM_NODES, HID, 8);
    // 5) GAT2 combine (+bias) -> h2 f32 (R0)
    gat_edge_k<1, false, false><<<dim3(MROWS), blk, 0, stream>>>(XL, XR, att2, bias2,
                                                                 h2, nullptr, nullptr);
    gat_node0_k<1, false, false><<<dim3(BSZ, 1), blk, 0, stream>>>(XL, XR, att2, bias2,
                                                                   h2, nullptr, nullptr);
    // 6) outputs
    head_k<<<dim3(BSZ, 2), blk, 0, stream>>>(h2, linw, linb, pooled, out);
    mean_k<<<dim3(BSZ, 2), blk, 0, stream>>>(h2, out);
}

// Round 6
// 951.693 us; speedup vs baseline: 1.2232x; 1.1325x over previous
//
#include <hip/hip_runtime.h>
#include <hip/hip_bf16.h>
#include <math.h>

// Problem constants (fixed by the reference)
constexpr int BSZ       = 64;
constexpr int SEQL      = 576;
constexpr int FTIN      = 768;
constexpr int HID       = 512;
constexpr int NNODE     = SEQL + 1;          // 577
constexpr int NUM_NODES = BSZ * NNODE;       // 36928
constexpr int MROWS     = BSZ * SEQL;        // 36864

using b8 = __attribute__((ext_vector_type(8))) __bf16;
using f4 = __attribute__((ext_vector_type(4))) float;
typedef unsigned short u16;

__device__ __forceinline__ float gelu_f(float x) {
    float x3 = x * x * x;
    return 0.5f * x * (1.0f + tanhf(0.7978845608028654f * (x + 0.044715f * x3)));
}
__device__ __forceinline__ float lrelu(float x) {
    return x > 0.0f ? x : 0.2f * x;
}
__device__ __forceinline__ u16 f2bf(float v) {
    __hip_bfloat16 b = __float2bfloat16(v);   // RNE
    return __builtin_bit_cast(u16, b);
}
__device__ __forceinline__ float bf2f(u16 u) {
    return __bfloat162float(__builtin_bit_cast(__hip_bfloat16, u));
}
__device__ __forceinline__ void split_bf(float v, u16& h, u16& l) {
    h = f2bf(v);
    l = f2bf(v - bf2f(h));
}
__device__ __forceinline__ void gl16(const void* g, void* l) {
    __builtin_amdgcn_global_load_lds(
        (const __attribute__((address_space(1))) unsigned int*)g,
        (__attribute__((address_space(3))) unsigned int*)l, 16, 0, 0);
}
__device__ __forceinline__ f4 mfma16(b8 a, b8 b, f4 c) {
    return __builtin_amdgcn_mfma_f32_16x16x32_bf16(a, b, c, 0, 0, 0);
}

// ---------------------------------------------------------------------------
// Weight prep: W fp32 [K x N] -> W^T hi/lo bf16 [N x K]
// ---------------------------------------------------------------------------
__global__ __launch_bounds__(256) void transpose_split_k(
    const float* __restrict__ W, u16* __restrict__ Th,
    u16* __restrict__ Tl, int K, int N)
{
    __shared__ float t[64][65];
    const int kb = blockIdx.x * 64, nb = blockIdx.y * 64;
    for (int i = threadIdx.x; i < 64 * 64; i += 256) {
        int r = i >> 6, c = i & 63;
        t[r][c] = W[(size_t)(kb + r) * N + nb + c];
    }
    __syncthreads();
    for (int i = threadIdx.x; i < 64 * 64; i += 256) {
        int r = i >> 6, c = i & 63;          // r: n index, c: k index
        float v = t[c][r];
        u16 h, l; split_bf(v, h, l);
        Th[(size_t)(nb + r) * K + kb + c] = h;
        Tl[(size_t)(nb + r) * K + kb + c] = l;
    }
}

// ---------------------------------------------------------------------------
// Fused bias: out[n] = (pb ? pb @ W_n : 0) + bias_n, n in [0,1024)
// ---------------------------------------------------------------------------
__global__ __launch_bounds__(256) void fuse_bias_k(
    const float* __restrict__ pb,
    const float* __restrict__ wA, const float* __restrict__ wB,
    const float* __restrict__ bA, const float* __restrict__ bB,
    float* __restrict__ out)
{
    const int n = blockIdx.x * 256 + threadIdx.x;   // grid 4
    const float* W = (n < 512) ? wA : wB;
    const int c = n & 511;
    float acc = 0.0f;
    if (pb) {
        for (int j = 0; j < 512; j++) acc = fmaf(pb[j], W[(size_t)j * 512 + c], acc);
    }
    out[n] = acc + ((n < 512) ? bA[c] : bB[c]);
}

// ---------------------------------------------------------------------------
// node-0 projection rows: XL/XR[b*577] = pooled[b] @ {wl,wr} + {bl,br}
// ---------------------------------------------------------------------------
__global__ __launch_bounds__(256) void node0_proj_k(
    const float* __restrict__ pooled,
    const float* __restrict__ wl, const float* __restrict__ wr,
    const float* __restrict__ bl, const float* __restrict__ br,
    float* __restrict__ XL, float* __restrict__ XR)
{
    const int b = blockIdx.x;                        // 64
    const int n = blockIdx.y * 256 + threadIdx.x;    // grid.y = 4 -> n < 1024
    __shared__ float p[HID];
    for (int k = threadIdx.x; k < HID; k += 256) p[k] = pooled[b * HID + k];
    __syncthreads();
    const float* W = (n < 512) ? wl : wr;
    const int c = n & 511;
    float acc = 0.0f;
    for (int k = 0; k < HID; k++) acc = fmaf(p[k], W[(size_t)k * 512 + c], acc);
    acc += (n < 512) ? bl[c] : br[c];
    const size_t row = (size_t)b * NNODE * HID;
    if (n < 512) XL[row + c] = acc; else XR[row + c] = acc;
}

// ---------------------------------------------------------------------------
// MFMA GEMM, hi/lo bf16 split (3-product), k-major conflict-free LDS regions.
// m97 structure; 1D grid, bijective XCD swizzle, col-fastest decode.
// MODE: 1 = gelu -> hi/lo bf16 (G1)
//       3 = transposed hi/lo write [N][K], no bias (weight-fusion prep)
//       4 = fp32 pair (XL cols 0-511 / XR 512-1023), row remap seq->node
//       5 = fp32 pair, plain rows with tail guard
// ---------------------------------------------------------------------------
template<int MODE, bool AF32>
__global__ __launch_bounds__(256, 4) void bgemm(
    const u16* __restrict__ Ah, const u16* __restrict__ Al,
    const float* __restrict__ Af,
    const u16* __restrict__ BTh, const u16* __restrict__ BTl,
    const float* __restrict__ bias,
    float* __restrict__ CfL, float* __restrict__ CfR,
    u16* __restrict__ Ch, u16* __restrict__ Cl,
    int M, int K, int nblk)
{
    __shared__ u16 lds[4][4096];   // [Ah,Al,Bh,Bl][8 regions x 512]

    // 1D grid, bijective XCD swizzle (gridDim.x % 8 == 0 for all big call sites)
    const int nwg = gridDim.x;
    const int p = blockIdx.x;
    const int lb = (nwg % 8 == 0) ? (p % 8) * (nwg / 8) + p / 8 : p;
    const int row0 = (lb / nblk) * 128, col0 = (lb % nblk) * 128;

    const int tid  = threadIdx.x;
    const int wid  = tid >> 6, lane = tid & 63;
    const int wr   = wid >> 1, wc = wid & 1;
    const int lrow = lane & 15, lk = lane >> 4;
    const int nt   = K >> 5;

    f4 acc[4][4] = {};
    float4 areg[4];

    for (int t = 0; t < nt; t++) {
        const int k0 = t << 5;

        // ---- stage (async gl16 issues first; reg-loads/ds_writes overlap)
#pragma unroll
        for (int i = 0; i < 2; i++) {
            const int r = wid * 2 + i;                       // region 0..7
            const int bcol = col0 + r * 16 + lrow;
            const size_t bgo = (size_t)bcol * K + k0 + lk * 8;
            gl16(BTh + bgo, &lds[2][r * 512]);
            gl16(BTl + bgo, &lds[3][r * 512]);
            if constexpr (!AF32) {
                int grow = row0 + r * 16 + lrow;
                if (grow >= M) grow = M - 1;                 // tail clamp
                const size_t ago = (size_t)grow * K + k0 + lk * 8;
                gl16(Ah + ago, &lds[0][r * 512]);
                gl16(Al + ago, &lds[1][r * 512]);
            }
        }
        if constexpr (AF32) {
#pragma unroll
            for (int q = 0; q < 4; q++) {
                const int ch = tid * 4 + q;                  // 0..1023
                const int r = ch >> 3, c4 = ch & 7;
                areg[q] = *(const float4*)(Af + (size_t)(row0 + r) * K + k0 + c4 * 4);
            }
#pragma unroll
            for (int q = 0; q < 4; q++) {
                const int ch = tid * 4 + q;
                const int r = ch >> 3, c4 = ch & 7;
                u16 h0, l0, h1, l1, h2, l2, h3, l3;
                split_bf(areg[q].x, h0, l0); split_bf(areg[q].y, h1, l1);
                split_bf(areg[q].z, h2, l2); split_bf(areg[q].w, h3, l3);
                const int off = (r >> 4) * 512 + ((c4 >> 1) * 16 + (r & 15)) * 8 + (c4 & 1) * 4;
                *(ushort4*)&lds[0][off] = make_ushort4(h0, h1, h2, h3);
                *(ushort4*)&lds[1][off] = make_ushort4(l0, l1, l2, l3);
            }
        }
        __syncthreads();   // drains vmcnt (gl16) + lgkm (ds_write)

        // ---- compute: fragment read = base + lane*16B (conflict-free) + 48 MFMA
        b8 a_h[4], b_h[4], tmp[4];
#pragma unroll
        for (int m = 0; m < 4; m++) a_h[m] = *(const b8*)&lds[0][(wr * 4 + m) * 512 + lane * 8];
#pragma unroll
        for (int n = 0; n < 4; n++) b_h[n] = *(const b8*)&lds[2][(wc * 4 + n) * 512 + lane * 8];
#pragma unroll
        for (int m = 0; m < 4; m++)
#pragma unroll
            for (int n = 0; n < 4; n++)
                acc[m][n] = mfma16(a_h[m], b_h[n], acc[m][n]);
        // A_lo x B_hi
#pragma unroll
        for (int m = 0; m < 4; m++) tmp[m] = *(const b8*)&lds[1][(wr * 4 + m) * 512 + lane * 8];
#pragma unroll
        for (int m = 0; m < 4; m++)
#pragma unroll
            for (int n = 0; n < 4; n++)
                acc[m][n] = mfma16(tmp[m], b_h[n], acc[m][n]);
        // A_hi x B_lo
#pragma unroll
        for (int n = 0; n < 4; n++) tmp[n] = *(const b8*)&lds[3][(wc * 4 + n) * 512 + lane * 8];
#pragma unroll
        for (int m = 0; m < 4; m++)
#pragma unroll
            for (int n = 0; n < 4; n++)
                acc[m][n] = mfma16(a_h[m], tmp[n], acc[m][n]);

        __syncthreads();   // LDS reads done before next stage overwrites
    }

    // ---- epilogue. D frag: row = 4*lk + reg, col = lrow (m89 layout)
    const int gcolbase = col0 + wc * 64;
    float biasn[4];
    if constexpr (MODE != 3) {
#pragma unroll
        for (int n = 0; n < 4; n++) biasn[n] = bias[gcolbase + n * 16 + lrow];
    }

#pragma unroll
    for (int m = 0; m < 4; m++) {
#pragma unroll
        for (int r = 0; r < 4; r++) {
            const int grow = row0 + wr * 64 + m * 16 + lk * 4 + r;
            if (MODE != 5 || grow < M) {
#pragma unroll
                for (int n = 0; n < 4; n++) {
                    const int gcol = gcolbase + n * 16 + lrow;
                    float v = acc[m][n][r];
                    if constexpr (MODE == 1) {
                        v = gelu_f(v + biasn[n]);
                        u16 h, l; split_bf(v, h, l);
                        Ch[(size_t)grow * HID + gcol] = h;
                        Cl[(size_t)grow * HID + gcol] = l;
                    } else if constexpr (MODE == 3) {
                        u16 h, l; split_bf(v, h, l);
                        Ch[(size_t)gcol * 512 + grow] = h;
                        Cl[(size_t)gcol * 512 + grow] = l;
                    } else {
                        v += biasn[n];
                        const int orow = (MODE == 4) ? (grow + grow / SEQL + 1) : grow;
                        if (gcol < 512) CfL[(size_t)orow * HID + gcol] = v;
                        else            CfR[(size_t)orow * HID + gcol - 512] = v;
                    }
                }
            }
        }
    }
}

// ---------------------------------------------------------------------------
// GAT combine, dst j >= 1: softmax over {src=0, src=j}. One block per node.
// ---------------------------------------------------------------------------
template<int HEADS, bool GELU, bool OSPLIT>
__global__ __launch_bounds__(256) void gat_edge_k(
    const float* __restrict__ xl, const float* __restrict__ xr,
    const float* __restrict__ att, const float* __restrict__ bias,
    float* __restrict__ outF, u16* __restrict__ outH, u16* __restrict__ outL)
{
    const int b = blockIdx.x / SEQL;
    const int j = blockIdx.x % SEQL;
    const size_t row0 = (size_t)(b * NNODE) * HID;
    const size_t rowj = (size_t)(b * NNODE + 1 + j) * HID;
    const int t = threadIdx.x;
    const int c = 2 * t;

    const float2 xl0  = *(const float2*)(xl + row0 + c);
    const float2 xljv = *(const float2*)(xl + rowj + c);
    const float2 xrjv = *(const float2*)(xr + rowj + c);
    const float2 attc = *(const float2*)(att + c);

    float e0 = attc.x * lrelu(xl0.x + xrjv.x) + attc.y * lrelu(xl0.y + xrjv.y);
    float e1 = attc.x * lrelu(xljv.x + xrjv.x) + attc.y * lrelu(xljv.y + xrjv.y);

#pragma unroll
    for (int off = 32; off; off >>= 1) {
        e0 += __shfl_down(e0, off, 64);
        e1 += __shfl_down(e1, off, 64);
    }
    __shared__ float s0[4], s1[4];
    const int w = t >> 6, lane = t & 63;
    if (lane == 0) { s0[w] = e0; s1[w] = e1; }
    __syncthreads();

    float E0, E1;
    if (HEADS == 4) { E0 = s0[w]; E1 = s1[w]; }
    else            { E0 = s0[0] + s0[1] + s0[2] + s0[3];
                      E1 = s1[0] + s1[1] + s1[2] + s1[3]; }

    const float m  = fmaxf(E0, E1);
    const float p0 = expf(E0 - m);
    const float p1 = expf(E1 - m);
    const float inv = 1.0f / (p0 + p1 + 1e-16f);
    const float a0 = p0 * inv, a1 = p1 * inv;

    float ox = a0 * xl0.x + a1 * xljv.x + bias[c + 0];
    float oy = a0 * xl0.y + a1 * xljv.y + bias[c + 1];
    if (GELU) { ox = gelu_f(ox); oy = gelu_f(oy); }
    if constexpr (OSPLIT) {
        u16 h0, l0, h1, l1;
        split_bf(ox, h0, l0); split_bf(oy, h1, l1);
        *(ushort2*)&outH[rowj + c] = make_ushort2(h0, h1);
        *(ushort2*)&outL[rowj + c] = make_ushort2(l0, l1);
    } else {
        *(float2*)(outF + rowj + c) = make_float2(ox, oy);
    }
}

// ---------------------------------------------------------------------------
// node-0 softmax path, stage A: e[b][s][h] = att_h . lrelu(xl[s] + xr[node0])
// One wave per source node. Grid = 36928/4 = 9232 blocks of 256.
// ---------------------------------------------------------------------------
template<int HEADS>
__global__ __launch_bounds__(256) void n0a_k(
    const float* __restrict__ XL, const float* __restrict__ XR,
    const float* __restrict__ att, float* __restrict__ es)
{
    const int gs = blockIdx.x * 4 + (threadIdx.x >> 6);   // global source id
    const int lane = threadIdx.x & 63;
    const int b = gs / NNODE, s = gs % NNODE;
    const float* xls = XL + (size_t)(b * NNODE + s) * HID;
    const float* xr0 = XR + (size_t)(b * NNODE) * HID;
    const int c = lane * 8;
    float e = 0.0f;
#pragma unroll
    for (int q = 0; q < 8; q += 4) {
        const float4 v = *(const float4*)(xls + c + q);
        const float4 r = *(const float4*)(xr0 + c + q);
        const float4 a = *(const float4*)(att + c + q);
        e = fmaf(a.x, lrelu(v.x + r.x), e);
        e = fmaf(a.y, lrelu(v.y + r.y), e);
        e = fmaf(a.z, lrelu(v.z + r.z), e);
        e = fmaf(a.w, lrelu(v.w + r.w), e);
    }
    e += __shfl_xor(e, 1, 64);
    e += __shfl_xor(e, 2, 64);
    e += __shfl_xor(e, 4, 64);
    e += __shfl_xor(e, 8, 64);
    if (HEADS == 1) {
        e += __shfl_xor(e, 16, 64);
        e += __shfl_xor(e, 32, 64);
        if (lane == 0) es[((size_t)b * NNODE + s) * 4] = e;
    } else {
        if ((lane & 15) == 0) es[((size_t)b * NNODE + s) * 4 + (lane >> 4)] = e;
    }
}

// ---------------------------------------------------------------------------
// stage B: per (b,h) softmax normalize: es <- exp(es-m); invS = 1/(sum+eps)
// ---------------------------------------------------------------------------
__global__ __launch_bounds__(256) void n0b_k(float* __restrict__ es,
                                             float* __restrict__ invS)
{
    const int b = blockIdx.x, h = blockIdx.y, t = threadIdx.x;
    __shared__ float red[256];
    float* e = es + (size_t)b * NNODE * 4 + h;      // stride 4
    float m = -INFINITY;
    for (int s = t; s < NNODE; s += 256) m = fmaxf(m, e[(size_t)s * 4]);
    red[t] = m; __syncthreads();
    for (int o = 128; o; o >>= 1) {
        if (t < o) red[t] = fmaxf(red[t], red[t + o]);
        __syncthreads();
    }
    m = red[0]; __syncthreads();
    float sum = 0.0f;
    for (int s = t; s < NNODE; s += 256) {
        const float p = expf(e[(size_t)s * 4] - m);
        e[(size_t)s * 4] = p;
        sum += p;
    }
    red[t] = sum; __syncthreads();
    for (int o = 128; o; o >>= 1) {
        if (t < o) red[t] += red[t + o];
        __syncthreads();
    }
    if (t == 0) invS[b * 4 + h] = 1.0f / (red[0] + 1e-16f);
}

// ---------------------------------------------------------------------------
// stage C: partial weighted sums over a source chunk. Grid (64, 8).
// ---------------------------------------------------------------------------
template<int HEADS>
__global__ __launch_bounds__(256) void n0c_k(
    const float* __restrict__ XL, const float* __restrict__ es,
    float* __restrict__ parts)
{
    const int b = blockIdx.x, split = blockIdx.y, t = threadIdx.x;
    const int c = t * 2;
    const int hh = (HEADS == 4) ? (c >> 7) : 0;
    const int s0 = split * 73;
    const int s1 = (s0 + 73 < NNODE) ? s0 + 73 : NNODE;
    float ax = 0.0f, ay = 0.0f;
    for (int s = s0; s < s1; s++) {
        const float p = es[((size_t)b * NNODE + s) * 4 + hh];
        const float2 v = *(const float2*)(XL + ((size_t)b * NNODE + s) * HID + c);
        ax = fmaf(p, v.x, ax);
        ay = fmaf(p, v.y, ay);
    }
    *(float2*)(parts + ((size_t)(b * 8 + split)) * HID + c) = make_float2(ax, ay);
}

// ---------------------------------------------------------------------------
// stage D: finalize node-0 output row. Grid 64.
// ---------------------------------------------------------------------------
template<int HEADS, bool GELU, bool OSPLIT>
__global__ __launch_bounds__(256) void n0d_k(
    const float* __restrict__ parts, const float* __restrict__ invS,
    const float* __restrict__ bias,
    float* __restrict__ outF, u16* __restrict__ outH, u16* __restrict__ outL)
{
    const int b = blockIdx.x, t = threadIdx.x;
    const int c = t * 2;
    const int hh = (HEADS == 4) ? (c >> 7) : 0;
    float ax = 0.0f, ay = 0.0f;
#pragma unroll
    for (int sp = 0; sp < 8; sp++) {
        const float2 v = *(const float2*)(parts + ((size_t)(b * 8 + sp)) * HID + c);
        ax += v.x; ay += v.y;
    }
    const float is = invS[b * 4 + hh];
    float ox = ax * is + bias[c];
    float oy = ay * is + bias[c + 1];
    if (GELU) { ox = gelu_f(ox); oy = gelu_f(oy); }
    const size_t row = (size_t)b * NNODE * HID;
    if constexpr (OSPLIT) {
        u16 h0, l0, h1, l1;
        split_bf(ox, h0, l0); split_bf(oy, h1, l1);
        *(ushort2*)&outH[row + c] = make_ushort2(h0, h1);
        *(ushort2*)&outL[row + c] = make_ushort2(l0, l1);
    } else {
        *(float2*)(outF + row + c) = make_float2(ox, oy);
    }
}

// ---------------------------------------------------------------------------
// graph_mean, s-split: grid (64, 8); block = 64 cols x 4 source chunks
// ---------------------------------------------------------------------------
__global__ __launch_bounds__(256) void mean_k(const float* __restrict__ h2,
                                              float* __restrict__ out)
{
    const int b = blockIdx.x;
    const int c = blockIdx.y * 64 + (threadIdx.x & 63);
    const int chunk = threadIdx.x >> 6;    // 0..3
    __shared__ float red[256];
    const int s0 = chunk * 145;
    const int s1 = (s0 + 145 < NNODE) ? s0 + 145 : NNODE;
    const float* p = h2 + (size_t)b * NNODE * HID + c;
    float acc = 0.0f;
    for (int s = s0; s < s1; s++) acc += p[(size_t)s * HID];
    red[threadIdx.x] = acc; __syncthreads();
    if (threadIdx.x < 128) red[threadIdx.x] += red[threadIdx.x + 128];
    __syncthreads();
    if (threadIdx.x < 64)
        out[(size_t)BSZ * HID + b * HID + blockIdx.y * 64 + threadIdx.x] =
            (red[threadIdx.x] + red[threadIdx.x + 64]) * (1.0f / NNODE);
}

__global__ __launch_bounds__(256) void head_k(
    const float* __restrict__ h2, const float* __restrict__ linw,
    const float* __restrict__ linb, const float* __restrict__ pooled,
    float* __restrict__ out)
{
    const int b = blockIdx.x;
    const int col = blockIdx.y * 256 + threadIdx.x;
    __shared__ float cls[HID];
    for (int k = threadIdx.x; k < HID; k += 256)
        cls[k] = h2[(size_t)(b * NNODE) * HID + k];
    __syncthreads();
    float acc = 0.0f;
    for (int k = 0; k < HID; k++)
        acc = fmaf(cls[k], linw[(size_t)k * HID + col], acc);
    out[b * HID + col] = acc + linb[col] + pooled[b * HID + col];
}

// ---------------------------------------------------------------------------
extern "C" void kernel_launch(void* const* d_in, const int* in_sizes, int n_in,
                              void* d_out, int out_size, void* d_ws, size_t ws_size,
                              hipStream_t stream)
{
    const float* hs     = (const float*)d_in[0];
    const float* pooled = (const float*)d_in[1];
    const float* pw1  = (const float*)d_in[2];  const float* pb1   = (const float*)d_in[3];
    const float* pw2  = (const float*)d_in[4];  const float* pb2   = (const float*)d_in[5];
    const float* wl1  = (const float*)d_in[6];  const float* bl1   = (const float*)d_in[7];
    const float* wr1  = (const float*)d_in[8];  const float* br1   = (const float*)d_in[9];
    const float* att1 = (const float*)d_in[10]; const float* bias1 = (const float*)d_in[11];
    const float* wl2  = (const float*)d_in[12]; const float* bl2   = (const float*)d_in[13];
    const float* wr2  = (const float*)d_in[14]; const float* br2   = (const float*)d_in[15];
    const float* att2 = (const float*)d_in[16]; const float* bias2 = (const float*)d_in[17];
    const float* linw = (const float*)d_in[18]; const float* linb  = (const float*)d_in[19];
    float* out = (float*)d_out;

    // ---- workspace arena: 3 rotating 72 MiB regions + weight/softmax region
    char* ws = (char*)d_ws;
    const size_t RSZ = 75637760;
    char* R0 = ws;                 // hH/hL -> h1H/h1L -> h2(f32)
    char* R1 = ws + RSZ;           // [prep scratch] -> xl1_f -> xl2_f
    char* R2 = ws + 2 * RSZ;       // xr1_f -> xr2_f
    u16*  Wr = (u16*)(ws + 3 * RSZ);

    // R0 tenants
    u16* hH  = (u16*)R0;
    u16* hL  = hH + (size_t)MROWS * HID;
    u16* h1H = (u16*)R0;
    u16* h1L = h1H + (size_t)NUM_NODES * HID;
    float* h2 = (float*)R0;
    // R1/R2 tenants
    float* XL = (float*)R1;
    float* XR = (float*)R2;
    // prep scratch inside R1 (consumed before XL is written)
    u16* prepBT_h = (u16*)R1;                       // [1024][512]
    u16* prepBT_l = prepBT_h + 1024 * 512;
    u16* pw1T_h   = prepBT_l + 1024 * 512;          // [512][768]
    u16* pw1T_l   = pw1T_h + 512 * FTIN;
    // persistent weight region (~4 MB) + node0-softmax scratch (~1.6 MB)
    u16* W1Th = Wr;                                 // fused pw2@[wl1|wr1], [1024][512]
    u16* W1Tl = W1Th + 1024 * 512;
    u16* BT2h = W1Tl + 1024 * 512;                  // [wl2|wr2]^T, [1024][512]
    u16* BT2l = BT2h + 1024 * 512;
    float* fb1 = (float*)(BT2l + 1024 * 512);       // fused bias layer1 [1024]
    float* fb2 = fb1 + 1024;                        // concat bias layer2 [1024]
    float* esP  = fb2 + 1024;                       // [64][577][4]
    float* invS = esP + (size_t)BSZ * NNODE * 4;    // [64][4]
    float* parts = invS + 256;                      // [64][8][512]

    const dim3 blk(256);

    // 0) weight prep
    transpose_split_k<<<dim3(8, 8), blk, 0, stream>>>(wl1, prepBT_h, prepBT_l, HID, HID);
    transpose_split_k<<<dim3(8, 8), blk, 0, stream>>>(wr1, prepBT_h + 512 * 512, prepBT_l + 512 * 512, HID, HID);
    transpose_split_k<<<dim3(12, 8), blk, 0, stream>>>(pw1, pw1T_h, pw1T_l, FTIN, HID);
    transpose_split_k<<<dim3(8, 8), blk, 0, stream>>>(wl2, BT2h, BT2l, HID, HID);
    transpose_split_k<<<dim3(8, 8), blk, 0, stream>>>(wr2, BT2h + 512 * 512, BT2l + 512 * 512, HID, HID);
    // W1' = pw2 @ [wl1|wr1], written transposed hi/lo (MODE 3); 4 rows x 8 cols
    bgemm<3, true><<<dim3(32), blk, 0, stream>>>(nullptr, nullptr, pw2, prepBT_h, prepBT_l,
                                                 nullptr, nullptr, nullptr, W1Th, W1Tl, 512, HID, 8);
    fuse_bias_k<<<dim3(4), blk, 0, stream>>>(pb2, wl1, wr1, bl1, br1, fb1);
    fuse_bias_k<<<dim3(4), blk, 0, stream>>>(nullptr, wl2, wr2, bl2, br2, fb2);

    // 1) h = gelu(hs @ pw1 + pb1) -> hH/hL (R0); 288 rows x 4 cols
    bgemm<1, true><<<dim3(1152), blk, 0, stream>>>(nullptr, nullptr, hs, pw1T_h, pw1T_l,
                                                   pb1, nullptr, nullptr, hH, hL, MROWS, FTIN, 4);
    // 2) fused GAT1 projections: xl1|xr1 = h @ W1' + fb1 (remap); 288 x 8
    bgemm<4, false><<<dim3(2304), blk, 0, stream>>>(hH, hL, nullptr, W1Th, W1Tl,
                                                    fb1, XL, XR, nullptr, nullptr, MROWS, HID, 8);
    node0_proj_k<<<dim3(BSZ, 4), blk, 0, stream>>>(pooled, wl1, wr1, bl1, br1, XL, XR);
    // 3) GAT1 combine (+bias, gelu) -> h1H/h1L (R0)
    gat_edge_k<4, true, true><<<dim3(MROWS), blk, 0, stream>>>(XL, XR, att1, bias1,
                                                               nullptr, h1H, h1L);
    n0a_k<4><<<dim3(NUM_NODES / 4), blk, 0, stream>>>(XL, XR, att1, esP);
    n0b_k<<<dim3(BSZ, 4), blk, 0, stream>>>(esP, invS);
    n0c_k<4><<<dim3(BSZ, 8), blk, 0, stream>>>(XL, esP, parts);
    n0d_k<4, true, true><<<dim3(BSZ), blk, 0, stream>>>(parts, invS, bias1,
                                                        nullptr, h1H, h1L);
    // 4) fused GAT2 projections: xl2|xr2 = h1 @ [wl2|wr2] + [bl2|br2]; 289 x 8
    bgemm<5, false><<<dim3(2312), blk, 0, stream>>>(h1H, h1L, nullptr, BT2h, BT2l,
                                                    fb2, XL, XR, nullptr, nullptr, NUM_NODES, HID, 8);
    // 5) GAT2 combine (+bias) -> h2 f32 (R0)
    gat_edge_k<1, false, false><<<dim3(MROWS), blk, 0, stream>>>(XL, XR, att2, bias2,
                                                                 h2, nullptr, nullptr);
    n0a_k<1><<<dim3(NUM_NODES / 4), blk, 0, stream>>>(XL, XR, att2, esP);
    n0b_k<<<dim3(BSZ, 1), blk, 0, stream>>>(esP, invS);
    n0c_k<1><<<dim3(BSZ, 8), blk, 0, stream>>>(XL, esP, parts);
    n0d_k<1, false, false><<<dim3(BSZ), blk, 0, stream>>>(parts, invS, bias2,
                                                          h2, nullptr, nullptr);
    // 6) outputs
    head_k<<<dim3(BSZ, 2), blk, 0, stream>>>(h2, linw, linb, pooled, out);
    mean_k<<<dim3(BSZ, 8), blk, 0, stream>>>(h2, out);
}